// Round 1
// baseline (20275.554 us; speedup 1.0000x reference)
//
#include <hip/hip_runtime.h>
#include <hip/hip_bf16.h>
#include <math.h>

#define D_MODEL 768
#define N_HEAD  12
#define HEAD    64
#define SEQ     1024
#define NLAYER  6
#define BATCH   4
#define NROWS   (BATCH*SEQ)   // 4096
#define VOCAB   50257
#define DFFN    3072

// ---------------- embedding: x = tok_emb[idx] + pos_emb[s] ----------------
__global__ __launch_bounds__(256)
void embed_kernel(const int* __restrict__ idx, const float* __restrict__ tok,
                  const float* __restrict__ pos, float* __restrict__ x) {
    int row = blockIdx.x;                 // b*SEQ + s
    int t = idx[row];
    int s = row & (SEQ - 1);
    const float* tp = tok + (size_t)t * D_MODEL;
    const float* pp = pos + (size_t)s * D_MODEL;
    float* xp = x + (size_t)row * D_MODEL;
    for (int i = threadIdx.x; i < D_MODEL; i += 256) xp[i] = tp[i] + pp[i];
}

// ---------------- layernorm: one block per row, D=768 ----------------
__global__ __launch_bounds__(256)
void ln_kernel(const float* __restrict__ in, const float* __restrict__ gw,
               const float* __restrict__ bw, float* __restrict__ out) {
    int row = blockIdx.x;
    int tid = threadIdx.x;
    const float* x = in + (size_t)row * D_MODEL;
    float v0 = x[tid], v1 = x[tid + 256], v2 = x[tid + 512];
    float s  = v0 + v1 + v2;
    float sq = v0*v0 + v1*v1 + v2*v2;
    #pragma unroll
    for (int o = 1; o < 64; o <<= 1) { s += __shfl_xor(s, o); sq += __shfl_xor(sq, o); }
    __shared__ float red[8];
    int wave = tid >> 6;
    if ((tid & 63) == 0) { red[wave] = s; red[4 + wave] = sq; }
    __syncthreads();
    s  = red[0] + red[1] + red[2] + red[3];
    sq = red[4] + red[5] + red[6] + red[7];
    float mean = s * (1.0f / D_MODEL);
    float var  = sq * (1.0f / D_MODEL) - mean * mean;
    float rstd = rsqrtf(var + 1e-5f);
    float* op = out + (size_t)row * D_MODEL;
    op[tid]       = (v0 - mean) * rstd * gw[tid]       + bw[tid];
    op[tid + 256] = (v1 - mean) * rstd * gw[tid + 256] + bw[tid + 256];
    op[tid + 512] = (v2 - mean) * rstd * gw[tid + 512] + bw[tid + 512];
}

// ---------------- fp32 tiled GEMM ----------------
// C[M,N] = A[M,K] @ B + bias (+GELU) (+res)
// BMODE 0: B[k*N+n]  (row-major [K,N])
// BMODE 1: B = per-head [H, D, HS]: B(k,n) = W[((n>>6)*K + k)*64 + (n&63)]
// BMODE 2: B(k,n) = B[n*K + k]  (row-major [N,K], i.e. Wlm)
// M must be a multiple of 128; K a multiple of 16; N bounds-checked.
template<int BMODE, bool GELU, bool RES>
__global__ __launch_bounds__(256)
void gemm_f32(const float* __restrict__ A, const float* __restrict__ B,
              const float* __restrict__ bias, const float* __restrict__ res,
              float* __restrict__ C, int M, int N, int K) {
    __shared__ float As[16][132];   // [k][m], padded
    __shared__ float Bs[16][132];   // [k][n], padded
    const int bm = blockIdx.y * 128;
    const int bn = blockIdx.x * 128;
    const int tid = threadIdx.x;
    const int tx = tid & 15, ty = tid >> 4;
    const int row0 = ty * 8, col0 = tx * 8;
    float acc[8][8] = {};
    for (int k0 = 0; k0 < K; k0 += 16) {
        #pragma unroll
        for (int i = 0; i < 8; ++i) {
            int lin = tid + i * 256;          // 0..2047
            int r = lin >> 4, c = lin & 15;   // m-row, k-col
            As[c][r] = A[(size_t)(bm + r) * K + (k0 + c)];
        }
        #pragma unroll
        for (int i = 0; i < 8; ++i) {
            int lin = tid + i * 256;
            if (BMODE == 2) {
                int r = lin & 15, c = lin >> 4;   // k, n  (coalesced along k)
                int n = bn + c;
                Bs[r][c] = (n < N) ? B[(size_t)n * K + (k0 + r)] : 0.0f;
            } else {
                int c = lin & 127, r = lin >> 7;  // n, k  (coalesced along n)
                int n = bn + c;
                float val;
                if (BMODE == 1) {
                    val = B[(size_t)((n >> 6) * K + (k0 + r)) * 64 + (n & 63)];
                } else {
                    val = (n < N) ? B[(size_t)(k0 + r) * N + n] : 0.0f;
                }
                Bs[r][c] = val;
            }
        }
        __syncthreads();
        #pragma unroll
        for (int kk = 0; kk < 16; ++kk) {
            float a[8], b[8];
            #pragma unroll
            for (int i = 0; i < 8; ++i) a[i] = As[kk][row0 + i];
            #pragma unroll
            for (int j = 0; j < 8; ++j) b[j] = Bs[kk][col0 + j];
            #pragma unroll
            for (int i = 0; i < 8; ++i)
                #pragma unroll
                for (int j = 0; j < 8; ++j)
                    acc[i][j] += a[i] * b[j];
        }
        __syncthreads();
    }
    #pragma unroll
    for (int i = 0; i < 8; ++i) {
        int m = bm + row0 + i;
        #pragma unroll
        for (int j = 0; j < 8; ++j) {
            int n = bn + col0 + j;
            if (n < N) {
                float vv = acc[i][j];
                if (bias) vv += bias[n];
                if (GELU) vv = 0.5f * vv * (1.0f + erff(vv * 0.70710678118654752f));
                if (RES)  vv += res[(size_t)m * N + n];
                C[(size_t)m * N + n] = vv;
            }
        }
    }
}

// ---------------- causal flash attention ----------------
// q,k,v,out layout: [B, S, H*HEAD] (head h occupies cols h*64..h*64+63)
// grid: (S/32, H, B); 256 threads; thread t: row r=t>>3 (of 32), dim group g=t&7 (8 dims)
__global__ __launch_bounds__(256)
void attn_kernel(const float* __restrict__ q, const float* __restrict__ k,
                 const float* __restrict__ v, float* __restrict__ out) {
    const int qt = blockIdx.x;
    const int h  = blockIdx.y;
    const int b  = blockIdx.z;
    const int tid = threadIdx.x;
    const int r = tid >> 3, g = tid & 7;
    __shared__ float qs[32][68];
    __shared__ float ks[32][68];
    __shared__ float vs[32][68];
    __shared__ float ss[32][33];
    const size_t base = (size_t)b * SEQ * D_MODEL + (size_t)h * HEAD;
    const float* qb = q + base;
    const float* kb = k + base;
    const float* vb = v + base;
    for (int i = tid; i < 32 * 64; i += 256) {
        int rr = i >> 6, cc = i & 63;
        qs[rr][cc] = qb[(size_t)(qt * 32 + rr) * D_MODEL + cc] * 0.125f; // 1/sqrt(64)
    }
    float o[8] = {0, 0, 0, 0, 0, 0, 0, 0};
    float mval = -INFINITY, l = 0.0f;
    __syncthreads();
    for (int kt = 0; kt <= qt; ++kt) {
        for (int i = tid; i < 32 * 64; i += 256) {
            int rr = i >> 6, cc = i & 63;
            ks[rr][cc] = kb[(size_t)(kt * 32 + rr) * D_MODEL + cc];
            vs[rr][cc] = vb[(size_t)(kt * 32 + rr) * D_MODEL + cc];
        }
        __syncthreads();
        float sc[4];
        {
            float s0 = 0, s1 = 0, s2 = 0, s3 = 0;
            const int j0 = g * 4;
            #pragma unroll 16
            for (int kk = 0; kk < 64; ++kk) {
                float qv = qs[r][kk];
                s0 += qv * ks[j0 + 0][kk];
                s1 += qv * ks[j0 + 1][kk];
                s2 += qv * ks[j0 + 2][kk];
                s3 += qv * ks[j0 + 3][kk];
            }
            sc[0] = s0; sc[1] = s1; sc[2] = s2; sc[3] = s3;
        }
        const int qg = qt * 32 + r;
        #pragma unroll
        for (int jj = 0; jj < 4; ++jj) {
            int jgl = kt * 32 + g * 4 + jj;
            if (jgl > qg) sc[jj] = -1e30f;   // causal mask
        }
        float tmax = fmaxf(fmaxf(sc[0], sc[1]), fmaxf(sc[2], sc[3]));
        #pragma unroll
        for (int ms = 1; ms < 8; ms <<= 1) tmax = fmaxf(tmax, __shfl_xor(tmax, ms));
        float mnew = fmaxf(mval, tmax);
        float alpha = __expf(mval - mnew);   // exp(-inf)=0 on first tile
        float p[4], psum = 0.0f;
        #pragma unroll
        for (int jj = 0; jj < 4; ++jj) { p[jj] = __expf(sc[jj] - mnew); psum += p[jj]; }
        #pragma unroll
        for (int ms = 1; ms < 8; ms <<= 1) psum += __shfl_xor(psum, ms);
        l = l * alpha + psum;
        mval = mnew;
        #pragma unroll
        for (int i = 0; i < 8; ++i) o[i] *= alpha;
        #pragma unroll
        for (int jj = 0; jj < 4; ++jj) ss[r][g * 4 + jj] = p[jj];
        __syncthreads();
        #pragma unroll 8
        for (int j = 0; j < 32; ++j) {
            float pv = ss[r][j];
            #pragma unroll
            for (int i = 0; i < 8; ++i) o[i] += pv * vs[j][g * 8 + i];
        }
        __syncthreads();
    }
    float inv = 1.0f / l;
    float* op = out + base + (size_t)(qt * 32 + r) * D_MODEL + g * 8;
    #pragma unroll
    for (int i = 0; i < 8; ++i) op[i] = o[i] * inv;
}

extern "C" void kernel_launch(void* const* d_in, const int* in_sizes, int n_in,
                              void* d_out, int out_size, void* d_ws, size_t ws_size,
                              hipStream_t stream) {
    const int*   idx     = (const int*)  d_in[0];
    const float* tok_emb = (const float*)d_in[1];
    const float* pos_emb = (const float*)d_in[2];
    const float* Wq      = (const float*)d_in[3];
    const float* bq      = (const float*)d_in[4];
    const float* Wk      = (const float*)d_in[5];
    const float* bk      = (const float*)d_in[6];
    const float* Wv      = (const float*)d_in[7];
    const float* bv      = (const float*)d_in[8];
    const float* Wproj   = (const float*)d_in[9];
    const float* bproj   = (const float*)d_in[10];
    const float* ln1g    = (const float*)d_in[11];
    const float* ln1b    = (const float*)d_in[12];
    const float* ln2g    = (const float*)d_in[13];
    const float* ln2b    = (const float*)d_in[14];
    const float* Wf1     = (const float*)d_in[15];
    const float* bf1     = (const float*)d_in[16];
    const float* Wf2     = (const float*)d_in[17];
    const float* bf2     = (const float*)d_in[18];
    const float* lnfg    = (const float*)d_in[19];
    const float* lnfb    = (const float*)d_in[20];
    const float* Wlm     = (const float*)d_in[21];
    float* outp = (float*)d_out;
    float* ws   = (float*)d_ws;

    const size_t NR = NROWS;               // 4096 rows
    float* x  = ws;                        // [4096,768]
    float* hb = x  + NR * D_MODEL;         // [4096,768] ln output
    float* qb = hb + NR * D_MODEL;         // [4096,768]
    float* kb = qb + NR * D_MODEL;
    float* vb = kb + NR * D_MODEL;
    float* ao = vb + NR * D_MODEL;         // attention concat output
    float* mid = qb;                       // [4096,3072] aliases q..ao (dead during FFN)
    // total: 6 * 4096 * 768 * 4B = 75.5 MB of workspace

    dim3 blk(256);
    dim3 g768(D_MODEL / 128, NR / 128);    // (6, 32)
    dim3 g3072(DFFN / 128, NR / 128);      // (24, 32)
    dim3 ga(SEQ / 32, N_HEAD, BATCH);      // (32, 12, 4)

    embed_kernel<<<NROWS, blk, 0, stream>>>(idx, tok_emb, pos_emb, x);

    for (int l = 0; l < NLAYER; ++l) {
        const float* wq_l = Wq + (size_t)l * N_HEAD * D_MODEL * HEAD;
        const float* wk_l = Wk + (size_t)l * N_HEAD * D_MODEL * HEAD;
        const float* wv_l = Wv + (size_t)l * N_HEAD * D_MODEL * HEAD;

        ln_kernel<<<NROWS, blk, 0, stream>>>(x, ln1g + l * D_MODEL, ln1b + l * D_MODEL, hb);

        gemm_f32<1, false, false><<<g768, blk, 0, stream>>>(hb, wq_l, bq + l * D_MODEL, nullptr, qb, NROWS, D_MODEL, D_MODEL);
        gemm_f32<1, false, false><<<g768, blk, 0, stream>>>(hb, wk_l, bk + l * D_MODEL, nullptr, kb, NROWS, D_MODEL, D_MODEL);
        gemm_f32<1, false, false><<<g768, blk, 0, stream>>>(hb, wv_l, bv + l * D_MODEL, nullptr, vb, NROWS, D_MODEL, D_MODEL);

        attn_kernel<<<ga, blk, 0, stream>>>(qb, kb, vb, ao);

        // x = x + ao @ Wproj + bproj   (in-place residual)
        gemm_f32<0, false, true><<<g768, blk, 0, stream>>>(ao, Wproj + (size_t)l * D_MODEL * D_MODEL,
                                                           bproj + l * D_MODEL, x, x, NROWS, D_MODEL, D_MODEL);

        ln_kernel<<<NROWS, blk, 0, stream>>>(x, ln2g + l * D_MODEL, ln2b + l * D_MODEL, hb);

        // mid = gelu(hb @ Wf1 + bf1)
        gemm_f32<0, true, false><<<g3072, blk, 0, stream>>>(hb, Wf1 + (size_t)l * D_MODEL * DFFN,
                                                            bf1 + l * DFFN, nullptr, mid, NROWS, DFFN, D_MODEL);
        // x = x + mid @ Wf2 + bf2
        gemm_f32<0, false, true><<<g768, blk, 0, stream>>>(mid, Wf2 + (size_t)l * DFFN * D_MODEL,
                                                           bf2 + l * D_MODEL, x, x, NROWS, D_MODEL, DFFN);
    }

    ln_kernel<<<NROWS, blk, 0, stream>>>(x, lnfg, lnfb, hb);

    dim3 gl((VOCAB + 127) / 128, NR / 128);  // (393, 32)
    gemm_f32<2, false, false><<<gl, blk, 0, stream>>>(hb, Wlm, nullptr, nullptr, outp, NROWS, VOCAB, D_MODEL);
}

// Round 2
// 5494.772 us; speedup vs baseline: 3.6900x; 3.6900x over previous
//
#include <hip/hip_runtime.h>
#include <hip/hip_bf16.h>
#include <math.h>

#define D_MODEL 768
#define N_HEAD  12
#define HEAD    64
#define SEQ     1024
#define NLAYER  6
#define BATCH   4
#define NROWS   (BATCH*SEQ)   // 4096
#define VOCAB   50257
#define VPAD    50304         // 393*128
#define DFFN    3072
#define DQKV    2304

typedef __attribute__((ext_vector_type(8))) __bf16 bf16x8;
typedef __attribute__((ext_vector_type(4))) float f32x4;
typedef __attribute__((ext_vector_type(4))) unsigned short u16x4;

__device__ inline unsigned short f2bf(float x) {
    __hip_bfloat16 h = __float2bfloat16(x);
    return *reinterpret_cast<unsigned short*>(&h);
}

// ---------------- embedding: x = tok_emb[idx] + pos_emb[s] ----------------
__global__ __launch_bounds__(256)
void embed_kernel(const int* __restrict__ idx, const float* __restrict__ tok,
                  const float* __restrict__ pos, float* __restrict__ x) {
    int row = blockIdx.x;
    int t = idx[row];
    int s = row & (SEQ - 1);
    const float* tp = tok + (size_t)t * D_MODEL;
    const float* pp = pos + (size_t)s * D_MODEL;
    float* xp = x + (size_t)row * D_MODEL;
    for (int i = threadIdx.x; i < D_MODEL; i += 256) xp[i] = tp[i] + pp[i];
}

// ---------------- layernorm: fp32 in, bf16 out ----------------
__global__ __launch_bounds__(256)
void ln_kernel(const float* __restrict__ in, const float* __restrict__ gw,
               const float* __restrict__ bw, unsigned short* __restrict__ out) {
    int row = blockIdx.x;
    int tid = threadIdx.x;
    const float* x = in + (size_t)row * D_MODEL;
    float v0 = x[tid], v1 = x[tid + 256], v2 = x[tid + 512];
    float s  = v0 + v1 + v2;
    float sq = v0*v0 + v1*v1 + v2*v2;
    #pragma unroll
    for (int o = 1; o < 64; o <<= 1) { s += __shfl_xor(s, o); sq += __shfl_xor(sq, o); }
    __shared__ float red[8];
    int wave = tid >> 6;
    if ((tid & 63) == 0) { red[wave] = s; red[4 + wave] = sq; }
    __syncthreads();
    s  = red[0] + red[1] + red[2] + red[3];
    sq = red[4] + red[5] + red[6] + red[7];
    float mean = s * (1.0f / D_MODEL);
    float var  = sq * (1.0f / D_MODEL) - mean * mean;
    float rstd = rsqrtf(var + 1e-5f);
    unsigned short* op = out + (size_t)row * D_MODEL;
    op[tid]       = f2bf((v0 - mean) * rstd * gw[tid]       + bw[tid]);
    op[tid + 256] = f2bf((v1 - mean) * rstd * gw[tid + 256] + bw[tid + 256]);
    op[tid + 512] = f2bf((v2 - mean) * rstd * gw[tid + 512] + bw[tid + 512]);
}

// ---------------- weight conversion ----------------
// transpose-convert: out_bf16[n*K + k] = in_f32(k,n)
// MODE 0: in[k*N + n]; MODE 1 (per-head qkv): in[((n>>6)*K + k)*64 + (n&63)]
template<int MODE>
__global__ __launch_bounds__(256)
void conv_transpose(const float* __restrict__ in, unsigned short* __restrict__ out,
                    int K, int N, size_t inLstride, size_t outLstride) {
    __shared__ float t[32][33];
    const int tx = threadIdx.x, ty = threadIdx.y;
    const int n0 = blockIdx.x * 32, k0 = blockIdx.y * 32;
    const float* ip = in + blockIdx.z * inLstride;
    unsigned short* op = out + blockIdx.z * outLstride;
    #pragma unroll
    for (int j = 0; j < 4; ++j) {
        int k = k0 + ty + j * 8, n = n0 + tx;
        float v = (MODE == 0) ? ip[(size_t)k * N + n]
                              : ip[(size_t)((n >> 6) * K + k) * 64 + (n & 63)];
        t[ty + j * 8][tx] = v;
    }
    __syncthreads();
    #pragma unroll
    for (int j = 0; j < 4; ++j) {
        int n = n0 + ty + j * 8, k = k0 + tx;
        op[(size_t)n * K + k] = f2bf(t[tx][ty + j * 8]);
    }
}

// Wlm [V,D] fp32 -> bf16 [VPAD,D] (pad rows zeroed)
__global__ __launch_bounds__(256)
void conv_lm(const float* __restrict__ in, unsigned short* __restrict__ out) {
    const int nchunks = VPAD * D_MODEL / 4;
    const int vchunks = VOCAB * D_MODEL / 4;
    for (int i = blockIdx.x * 256 + threadIdx.x; i < nchunks; i += gridDim.x * 256) {
        u16x4 o;
        if (i < vchunks) {
            float4 v = reinterpret_cast<const float4*>(in)[i];
            o[0] = f2bf(v.x); o[1] = f2bf(v.y); o[2] = f2bf(v.z); o[3] = f2bf(v.w);
        } else { o[0] = 0; o[1] = 0; o[2] = 0; o[3] = 0; }
        reinterpret_cast<u16x4*>(out)[i] = o;
    }
}

// bqkv[l][n] = concat(bq,bk,bv)
__global__ __launch_bounds__(256)
void conv_bias(const float* __restrict__ bq, const float* __restrict__ bk,
               const float* __restrict__ bv, float* __restrict__ out) {
    int i = blockIdx.x * 256 + threadIdx.x;
    if (i >= NLAYER * DQKV) return;
    int l = i / DQKV, n = i % DQKV;
    float v;
    if (n < 768)        v = bq[l * 768 + n];
    else if (n < 1536)  v = bk[l * 768 + n - 768];
    else                v = bv[l * 768 + n - 1536];
    out[i] = v;
}

// ---------------- bf16 MFMA GEMM ----------------
// C[M,N] = A[M,K](bf16) @ B[N,K](bf16)^T + bias (+GELU) (+res)
// 128x128 tile, BK=64, 4 waves of 64x64, k-chunk-major LDS (conflict-free).
// M%128==0, K%64==0, B padded to N%128==0 rows; stores bounds-check col<N.
template<int OUTF /*0=f32,1=bf16*/, bool GELU, bool RES>
__global__ __launch_bounds__(256)
void gemm_mfma(const unsigned short* __restrict__ A, const unsigned short* __restrict__ B,
               const float* __restrict__ bias, const float* __restrict__ res,
               void* __restrict__ Cout, int M, int N, int K) {
    __shared__ bf16x8 As[1024];   // [c][row]: index c*128+row, 16KB
    __shared__ bf16x8 Bs[1024];
    const int bm = blockIdx.y * 128, bn = blockIdx.x * 128;
    const int tid = threadIdx.x;
    const int l = tid & 63, w = tid >> 6;
    const int wr = (w >> 1) * 64, wc = (w & 1) * 64;
    f32x4 acc[4][4] = {};
    for (int k0 = 0; k0 < K; k0 += 64) {
        #pragma unroll
        for (int p = 0; p < 4; ++p) {
            int u = p * 256 + tid;
            int row = u & 127, c = u >> 7;
            const unsigned short* ga = A + (size_t)(bm + row) * K + k0 + c * 8;
            const unsigned short* gb = B + (size_t)(bn + row) * K + k0 + c * 8;
            __builtin_amdgcn_global_load_lds(
                (const __attribute__((address_space(1))) unsigned int*)ga,
                (__attribute__((address_space(3))) unsigned int*)(&As[u]), 16, 0, 0);
            __builtin_amdgcn_global_load_lds(
                (const __attribute__((address_space(1))) unsigned int*)gb,
                (__attribute__((address_space(3))) unsigned int*)(&Bs[u]), 16, 0, 0);
        }
        __syncthreads();
        #pragma unroll
        for (int s = 0; s < 2; ++s) {
            const int cidx = s * 4 + (l >> 4);
            bf16x8 af[4], bfr[4];
            #pragma unroll
            for (int mi = 0; mi < 4; ++mi) af[mi]  = As[cidx * 128 + wr + mi * 16 + (l & 15)];
            #pragma unroll
            for (int ni = 0; ni < 4; ++ni) bfr[ni] = Bs[cidx * 128 + wc + ni * 16 + (l & 15)];
            #pragma unroll
            for (int mi = 0; mi < 4; ++mi)
                #pragma unroll
                for (int ni = 0; ni < 4; ++ni)
                    acc[mi][ni] = __builtin_amdgcn_mfma_f32_16x16x32_bf16(
                        af[mi], bfr[ni], acc[mi][ni], 0, 0, 0);
        }
        __syncthreads();
    }
    // epilogue: C/D layout col=lane&15, row=(lane>>4)*4+r
    #pragma unroll
    for (int mi = 0; mi < 4; ++mi) {
        #pragma unroll
        for (int r = 0; r < 4; ++r) {
            const int row = bm + wr + mi * 16 + (l >> 4) * 4 + r;
            #pragma unroll
            for (int ni = 0; ni < 4; ++ni) {
                const int col = bn + wc + ni * 16 + (l & 15);
                if (col < N) {
                    float v = acc[mi][ni][r];
                    if (bias) v += bias[col];
                    if (GELU) v = 0.5f * v * (1.0f + erff(v * 0.70710678118654752f));
                    if (RES)  v += res[(size_t)row * N + col];
                    if (OUTF == 0) ((float*)Cout)[(size_t)row * N + col] = v;
                    else ((unsigned short*)Cout)[(size_t)row * N + col] = f2bf(v);
                }
            }
        }
    }
}

// ---------------- causal flash attention (fp32) ----------------
// qkv: [B*S, 2304] fp32 (q at h*64, k at +768, v at +1536); out ao: [B*S, 768] bf16
__global__ __launch_bounds__(256)
void attn_kernel(const float* __restrict__ qkv, unsigned short* __restrict__ out) {
    const int qt = blockIdx.x;
    const int h  = blockIdx.y;
    const int b  = blockIdx.z;
    const int tid = threadIdx.x;
    const int r = tid >> 3, g = tid & 7;
    __shared__ float qs[32][68];
    __shared__ float ks[32][68];
    __shared__ float vs[32][68];
    __shared__ float ss[32][33];
    const float* qb = qkv + (size_t)b * SEQ * DQKV + h * HEAD;
    for (int i = tid; i < 32 * 64; i += 256) {
        int rr = i >> 6, cc = i & 63;
        qs[rr][cc] = qb[(size_t)(qt * 32 + rr) * DQKV + cc] * 0.125f;
    }
    float o[8] = {0, 0, 0, 0, 0, 0, 0, 0};
    float mval = -INFINITY, lsum = 0.0f;
    __syncthreads();
    for (int kt = 0; kt <= qt; ++kt) {
        for (int i = tid; i < 32 * 64; i += 256) {
            int rr = i >> 6, cc = i & 63;
            const float* rp = qb + (size_t)(kt * 32 + rr) * DQKV + cc;
            ks[rr][cc] = rp[768];
            vs[rr][cc] = rp[1536];
        }
        __syncthreads();
        float sc[4];
        {
            float s0 = 0, s1 = 0, s2 = 0, s3 = 0;
            const int j0 = g * 4;
            #pragma unroll 16
            for (int kk = 0; kk < 64; ++kk) {
                float qv = qs[r][kk];
                s0 += qv * ks[j0 + 0][kk];
                s1 += qv * ks[j0 + 1][kk];
                s2 += qv * ks[j0 + 2][kk];
                s3 += qv * ks[j0 + 3][kk];
            }
            sc[0] = s0; sc[1] = s1; sc[2] = s2; sc[3] = s3;
        }
        const int qg = qt * 32 + r;
        #pragma unroll
        for (int jj = 0; jj < 4; ++jj) {
            int jgl = kt * 32 + g * 4 + jj;
            if (jgl > qg) sc[jj] = -1e30f;
        }
        float tmax = fmaxf(fmaxf(sc[0], sc[1]), fmaxf(sc[2], sc[3]));
        #pragma unroll
        for (int ms = 1; ms < 8; ms <<= 1) tmax = fmaxf(tmax, __shfl_xor(tmax, ms));
        float mnew = fmaxf(mval, tmax);
        float alpha = __expf(mval - mnew);
        float p[4], psum = 0.0f;
        #pragma unroll
        for (int jj = 0; jj < 4; ++jj) { p[jj] = __expf(sc[jj] - mnew); psum += p[jj]; }
        #pragma unroll
        for (int ms = 1; ms < 8; ms <<= 1) psum += __shfl_xor(psum, ms);
        lsum = lsum * alpha + psum;
        mval = mnew;
        #pragma unroll
        for (int i = 0; i < 8; ++i) o[i] *= alpha;
        #pragma unroll
        for (int jj = 0; jj < 4; ++jj) ss[r][g * 4 + jj] = p[jj];
        __syncthreads();
        #pragma unroll 8
        for (int j = 0; j < 32; ++j) {
            float pv = ss[r][j];
            #pragma unroll
            for (int i = 0; i < 8; ++i) o[i] += pv * vs[j][g * 8 + i];
        }
        __syncthreads();
    }
    float inv = 1.0f / lsum;
    unsigned short* op = out + ((size_t)(b * SEQ + qt * 32 + r)) * D_MODEL + h * HEAD + g * 8;
    #pragma unroll
    for (int i = 0; i < 8; ++i) op[i] = f2bf(o[i] * inv);
}

extern "C" void kernel_launch(void* const* d_in, const int* in_sizes, int n_in,
                              void* d_out, int out_size, void* d_ws, size_t ws_size,
                              hipStream_t stream) {
    const int*   idx     = (const int*)  d_in[0];
    const float* tok_emb = (const float*)d_in[1];
    const float* pos_emb = (const float*)d_in[2];
    const float* Wq      = (const float*)d_in[3];
    const float* bq      = (const float*)d_in[4];
    const float* Wk      = (const float*)d_in[5];
    const float* bk      = (const float*)d_in[6];
    const float* Wv      = (const float*)d_in[7];
    const float* bv      = (const float*)d_in[8];
    const float* Wproj   = (const float*)d_in[9];
    const float* bproj   = (const float*)d_in[10];
    const float* ln1g    = (const float*)d_in[11];
    const float* ln1b    = (const float*)d_in[12];
    const float* ln2g    = (const float*)d_in[13];
    const float* ln2b    = (const float*)d_in[14];
    const float* Wf1     = (const float*)d_in[15];
    const float* bf1     = (const float*)d_in[16];
    const float* Wf2     = (const float*)d_in[17];
    const float* bf2     = (const float*)d_in[18];
    const float* lnfg    = (const float*)d_in[19];
    const float* lnfb    = (const float*)d_in[20];
    const float* Wlm     = (const float*)d_in[21];
    float* outp = (float*)d_out;

    // ---- workspace layout (256B aligned) ----
    char* base = (char*)d_ws;
    size_t off = 0;
    auto alloc = [&](size_t bytes) -> void* {
        void* p = base + off;
        off = (off + bytes + 255) & ~(size_t)255;
        return p;
    };
    float*          x      = (float*)         alloc((size_t)NROWS * D_MODEL * 4);
    float*          qkv    = (float*)         alloc((size_t)NROWS * DQKV * 4);
    unsigned short* hb     = (unsigned short*)alloc((size_t)NROWS * D_MODEL * 2);
    unsigned short* ao     = (unsigned short*)alloc((size_t)NROWS * D_MODEL * 2);
    unsigned short* mid    = (unsigned short*)alloc((size_t)NROWS * DFFN * 2);
    unsigned short* Wqkvb  = (unsigned short*)alloc((size_t)NLAYER * DQKV * D_MODEL * 2);
    unsigned short* Wprojb = (unsigned short*)alloc((size_t)NLAYER * D_MODEL * D_MODEL * 2);
    unsigned short* Wf1b   = (unsigned short*)alloc((size_t)NLAYER * DFFN * D_MODEL * 2);
    unsigned short* Wf2b   = (unsigned short*)alloc((size_t)NLAYER * D_MODEL * DFFN * 2);
    unsigned short* Wlmb   = (unsigned short*)alloc((size_t)VPAD * D_MODEL * 2);
    float*          bqkv   = (float*)         alloc((size_t)NLAYER * DQKV * 4);

    dim3 blk(256);
    dim3 tblk(32, 8);

    // ---- weight conversion (per call; deterministic) ----
    conv_lm<<<2048, blk, 0, stream>>>(Wlm, Wlmb);
    conv_transpose<1><<<dim3(24, 24, 6), tblk, 0, stream>>>(Wq, Wqkvb,                 768, 768,  (size_t)768*768,  (size_t)DQKV*768);
    conv_transpose<1><<<dim3(24, 24, 6), tblk, 0, stream>>>(Wk, Wqkvb + 768*768,       768, 768,  (size_t)768*768,  (size_t)DQKV*768);
    conv_transpose<1><<<dim3(24, 24, 6), tblk, 0, stream>>>(Wv, Wqkvb + 2*768*768,     768, 768,  (size_t)768*768,  (size_t)DQKV*768);
    conv_transpose<0><<<dim3(24, 24, 6), tblk, 0, stream>>>(Wproj, Wprojb,             768, 768,  (size_t)768*768,  (size_t)768*768);
    conv_transpose<0><<<dim3(96, 24, 6), tblk, 0, stream>>>(Wf1, Wf1b,                 768, 3072, (size_t)768*3072, (size_t)3072*768);
    conv_transpose<0><<<dim3(24, 96, 6), tblk, 0, stream>>>(Wf2, Wf2b,                 3072, 768, (size_t)3072*768, (size_t)768*3072);
    conv_bias<<<(NLAYER * DQKV + 255) / 256, blk, 0, stream>>>(bq, bk, bv, bqkv);

    // ---- forward ----
    embed_kernel<<<NROWS, blk, 0, stream>>>(idx, tok_emb, pos_emb, x);

    dim3 gqkv(DQKV / 128, NROWS / 128);   // (18, 32)
    dim3 g768(D_MODEL / 128, NROWS / 128);// (6, 32)
    dim3 g3072(DFFN / 128, NROWS / 128);  // (24, 32)
    dim3 ga(SEQ / 32, N_HEAD, BATCH);     // (32, 12, 4)

    for (int l = 0; l < NLAYER; ++l) {
        ln_kernel<<<NROWS, blk, 0, stream>>>(x, ln1g + l * D_MODEL, ln1b + l * D_MODEL, hb);

        gemm_mfma<0, false, false><<<gqkv, blk, 0, stream>>>(
            hb, Wqkvb + (size_t)l * DQKV * D_MODEL, bqkv + l * DQKV, nullptr,
            qkv, NROWS, DQKV, D_MODEL);

        attn_kernel<<<ga, blk, 0, stream>>>(qkv, ao);

        gemm_mfma<0, false, true><<<g768, blk, 0, stream>>>(
            ao, Wprojb + (size_t)l * D_MODEL * D_MODEL, bproj + l * D_MODEL, x,
            x, NROWS, D_MODEL, D_MODEL);

        ln_kernel<<<NROWS, blk, 0, stream>>>(x, ln2g + l * D_MODEL, ln2b + l * D_MODEL, hb);

        gemm_mfma<1, true, false><<<g3072, blk, 0, stream>>>(
            hb, Wf1b + (size_t)l * DFFN * D_MODEL, bf1 + l * DFFN, nullptr,
            mid, NROWS, DFFN, D_MODEL);

        gemm_mfma<0, false, true><<<g768, blk, 0, stream>>>(
            mid, Wf2b + (size_t)l * D_MODEL * DFFN, bf2 + l * D_MODEL, x,
            x, NROWS, D_MODEL, DFFN);
    }

    ln_kernel<<<NROWS, blk, 0, stream>>>(x, lnfg, lnfb, hb);

    dim3 gl(VPAD / 128, NROWS / 128);     // (393, 32)
    gemm_mfma<0, false, false><<<gl, blk, 0, stream>>>(
        hb, Wlmb, nullptr, nullptr, outp, NROWS, VOCAB, D_MODEL);
}

// Round 3
// 3562.071 us; speedup vs baseline: 5.6921x; 1.5426x over previous
//
#include <hip/hip_runtime.h>
#include <hip/hip_bf16.h>
#include <math.h>

#define D_MODEL 768
#define N_HEAD  12
#define HEAD    64
#define SEQ     1024
#define NLAYER  6
#define BATCH   4
#define NROWS   (BATCH*SEQ)   // 4096
#define VOCAB   50257
#define VPAD    50304         // 393*128
#define DFFN    3072
#define DQKV    2304

typedef __attribute__((ext_vector_type(8))) __bf16 bf16x8;
typedef __attribute__((ext_vector_type(4))) float f32x4;
typedef __attribute__((ext_vector_type(4))) unsigned short u16x4;

__device__ inline unsigned short f2bf(float x) {
    __hip_bfloat16 h = __float2bfloat16(x);
    return *reinterpret_cast<unsigned short*>(&h);
}

// ---------------- embedding ----------------
__global__ __launch_bounds__(256)
void embed_kernel(const int* __restrict__ idx, const float* __restrict__ tok,
                  const float* __restrict__ pos, float* __restrict__ x) {
    int row = blockIdx.x;
    int t = idx[row];
    int s = row & (SEQ - 1);
    const float* tp = tok + (size_t)t * D_MODEL;
    const float* pp = pos + (size_t)s * D_MODEL;
    float* xp = x + (size_t)row * D_MODEL;
    for (int i = threadIdx.x; i < D_MODEL; i += 256) xp[i] = tp[i] + pp[i];
}

// ---------------- layernorm: fp32 in, bf16 out ----------------
__global__ __launch_bounds__(256)
void ln_kernel(const float* __restrict__ in, const float* __restrict__ gw,
               const float* __restrict__ bw, unsigned short* __restrict__ out) {
    int row = blockIdx.x;
    int tid = threadIdx.x;
    const float* x = in + (size_t)row * D_MODEL;
    float v0 = x[tid], v1 = x[tid + 256], v2 = x[tid + 512];
    float s  = v0 + v1 + v2;
    float sq = v0*v0 + v1*v1 + v2*v2;
    #pragma unroll
    for (int o = 1; o < 64; o <<= 1) { s += __shfl_xor(s, o); sq += __shfl_xor(sq, o); }
    __shared__ float red[8];
    int wave = tid >> 6;
    if ((tid & 63) == 0) { red[wave] = s; red[4 + wave] = sq; }
    __syncthreads();
    s  = red[0] + red[1] + red[2] + red[3];
    sq = red[4] + red[5] + red[6] + red[7];
    float mean = s * (1.0f / D_MODEL);
    float var  = sq * (1.0f / D_MODEL) - mean * mean;
    float rstd = rsqrtf(var + 1e-5f);
    unsigned short* op = out + (size_t)row * D_MODEL;
    op[tid]       = f2bf((v0 - mean) * rstd * gw[tid]       + bw[tid]);
    op[tid + 256] = f2bf((v1 - mean) * rstd * gw[tid + 256] + bw[tid + 256]);
    op[tid + 512] = f2bf((v2 - mean) * rstd * gw[tid + 512] + bw[tid + 512]);
}

// ---------------- weight conversion ----------------
template<int MODE>
__global__ __launch_bounds__(256)
void conv_transpose(const float* __restrict__ in, unsigned short* __restrict__ out,
                    int K, int N, size_t inLstride, size_t outLstride) {
    __shared__ float t[32][33];
    const int tx = threadIdx.x, ty = threadIdx.y;
    const int n0 = blockIdx.x * 32, k0 = blockIdx.y * 32;
    const float* ip = in + blockIdx.z * inLstride;
    unsigned short* op = out + blockIdx.z * outLstride;
    #pragma unroll
    for (int j = 0; j < 4; ++j) {
        int k = k0 + ty + j * 8, n = n0 + tx;
        float v = (MODE == 0) ? ip[(size_t)k * N + n]
                              : ip[(size_t)((n >> 6) * K + k) * 64 + (n & 63)];
        t[ty + j * 8][tx] = v;
    }
    __syncthreads();
    #pragma unroll
    for (int j = 0; j < 4; ++j) {
        int n = n0 + ty + j * 8, k = k0 + tx;
        op[(size_t)n * K + k] = f2bf(t[tx][ty + j * 8]);
    }
}

__global__ __launch_bounds__(256)
void conv_lm(const float* __restrict__ in, unsigned short* __restrict__ out) {
    const int nchunks = VPAD * D_MODEL / 4;
    const int vchunks = VOCAB * D_MODEL / 4;
    for (int i = blockIdx.x * 256 + threadIdx.x; i < nchunks; i += gridDim.x * 256) {
        u16x4 o;
        if (i < vchunks) {
            float4 v = reinterpret_cast<const float4*>(in)[i];
            o[0] = f2bf(v.x); o[1] = f2bf(v.y); o[2] = f2bf(v.z); o[3] = f2bf(v.w);
        } else { o[0] = 0; o[1] = 0; o[2] = 0; o[3] = 0; }
        reinterpret_cast<u16x4*>(out)[i] = o;
    }
}

__global__ __launch_bounds__(256)
void conv_bias(const float* __restrict__ bq, const float* __restrict__ bk,
               const float* __restrict__ bv, float* __restrict__ out) {
    int i = blockIdx.x * 256 + threadIdx.x;
    if (i >= NLAYER * DQKV) return;
    int l = i / DQKV, n = i % DQKV;
    float v;
    if (n < 768)        v = bq[l * 768 + n];
    else if (n < 1536)  v = bk[l * 768 + n - 768];
    else                v = bv[l * 768 + n - 1536];
    out[i] = v;
}

// ---------------- bf16 MFMA GEMM (1D grid, XCD row-chunked swizzle) ----------------
// C[M,N] = A[M,K](bf16) @ B[N,K](bf16)^T + bias (+GELU) (+res)
// launch: grid = (N_tiles * 32) 1D blocks; M == 4096 (32 row-tiles) required.
template<int OUTF /*0=f32,1=bf16*/, bool GELU, bool RES>
__global__ __launch_bounds__(256)
void gemm_mfma(const unsigned short* __restrict__ A, const unsigned short* __restrict__ B,
               const float* __restrict__ bias, const float* __restrict__ res,
               void* __restrict__ Cout, int M, int N, int K) {
    __shared__ bf16x8 As[1024];   // [c][row]: index c*128+row, 16KB
    __shared__ bf16x8 Bs[1024];
    // XCD swizzle: xcd = bid%8 owns 4 contiguous by rows; bx sweeps fastest.
    const int gx = gridDim.x >> 5;
    const int bid = blockIdx.x;
    const int slot = bid >> 3;
    const int q = slot / gx;
    const int by = (bid & 7) * 4 + q;
    const int bx = slot - q * gx;
    const int bm = by * 128, bn = bx * 128;
    const int tid = threadIdx.x;
    const int l = tid & 63, w = tid >> 6;
    const int wr = (w >> 1) * 64, wc = (w & 1) * 64;
    f32x4 acc[4][4] = {};
    for (int k0 = 0; k0 < K; k0 += 64) {
        #pragma unroll
        for (int p = 0; p < 4; ++p) {
            int u = p * 256 + tid;
            int row = u & 127, c = u >> 7;
            const unsigned short* ga = A + (size_t)(bm + row) * K + k0 + c * 8;
            const unsigned short* gb = B + (size_t)(bn + row) * K + k0 + c * 8;
            __builtin_amdgcn_global_load_lds(
                (const __attribute__((address_space(1))) unsigned int*)ga,
                (__attribute__((address_space(3))) unsigned int*)(&As[u]), 16, 0, 0);
            __builtin_amdgcn_global_load_lds(
                (const __attribute__((address_space(1))) unsigned int*)gb,
                (__attribute__((address_space(3))) unsigned int*)(&Bs[u]), 16, 0, 0);
        }
        __syncthreads();
        #pragma unroll
        for (int s = 0; s < 2; ++s) {
            const int cidx = s * 4 + (l >> 4);
            bf16x8 af[4], bfr[4];
            #pragma unroll
            for (int mi = 0; mi < 4; ++mi) af[mi]  = As[cidx * 128 + wr + mi * 16 + (l & 15)];
            #pragma unroll
            for (int ni = 0; ni < 4; ++ni) bfr[ni] = Bs[cidx * 128 + wc + ni * 16 + (l & 15)];
            #pragma unroll
            for (int mi = 0; mi < 4; ++mi)
                #pragma unroll
                for (int ni = 0; ni < 4; ++ni)
                    acc[mi][ni] = __builtin_amdgcn_mfma_f32_16x16x32_bf16(
                        af[mi], bfr[ni], acc[mi][ni], 0, 0, 0);
        }
        __syncthreads();
    }
    #pragma unroll
    for (int mi = 0; mi < 4; ++mi) {
        #pragma unroll
        for (int r = 0; r < 4; ++r) {
            const int row = bm + wr + mi * 16 + (l >> 4) * 4 + r;
            #pragma unroll
            for (int ni = 0; ni < 4; ++ni) {
                const int col = bn + wc + ni * 16 + (l & 15);
                if (col < N) {
                    float v = acc[mi][ni][r];
                    if (bias) v += bias[col];
                    if (GELU) v = 0.5f * v * (1.0f + erff(v * 0.70710678118654752f));
                    if (RES)  v += res[(size_t)row * N + col];
                    if (OUTF == 0) ((float*)Cout)[(size_t)row * N + col] = v;
                    else ((unsigned short*)Cout)[(size_t)row * N + col] = f2bf(v);
                }
            }
        }
    }
}

// ---------------- bf16 MFMA causal flash attention ----------------
// qkv: bf16 [NROWS][2304] (Q at h*64, K at +768, V at +1536); ao: bf16 [NROWS][768]
// grid (16, 12, 4), 256 threads. Block handles 64 q-rows; wave w owns 16 rows.
// Per KV tile (32 rows): QK^T (4 mfma), online softmax, P via LDS transpose, PV (4 mfma).
__global__ __launch_bounds__(256)
void attn_mfma(const unsigned short* __restrict__ qkv, unsigned short* __restrict__ ao) {
    const int qt = gridDim.x - 1 - blockIdx.x;   // heavy blocks first
    const int h = blockIdx.y, b = blockIdx.z;
    const int tid = threadIdx.x;
    const int w = tid >> 6, l = tid & 63;
    const int c = l & 15, g = l >> 4;

    __shared__ unsigned short Ks[32 * 64];       // row-major, 16B-chunk XOR swizzle
    __shared__ unsigned short Vt[64 * 40];       // [d][krow], row pad 40 halves
    __shared__ unsigned int   Ps[4][16 * 20];    // per-wave P transpose, [q][20 words]

    const unsigned short* base = qkv + (size_t)(b * SEQ) * DQKV + h * HEAD;
    const int q0 = qt * 64 + w * 16;

    // Q fragments (A-operand): row = c, k = ks*32 + g*8 + j
    bf16x8 qf[2];
    {
        const unsigned short* qp = base + (size_t)(q0 + c) * DQKV + g * 8;
        qf[0] = *reinterpret_cast<const bf16x8*>(qp);
        qf[1] = *reinterpret_cast<const bf16x8*>(qp + 32);
    }

    f32x4 o_acc[4] = {};                          // [dt]; row=g*4+r, col=dt*16+c
    float m_run[4]  = {-INFINITY, -INFINITY, -INFINITY, -INFINITY};
    float l_run[4]  = {0.f, 0.f, 0.f, 0.f};

    const int srow = tid >> 3, schunk = tid & 7;  // K staging: 32 rows x 8 chunks
    const int vd = tid & 63, vw = tid >> 6;       // V staging: 64 cols x 4 k-groups

    const int nkt = 2 * qt + 2;
    for (int kt = 0; kt < nkt; ++kt) {
        // ---- stage K tile (swizzled row-major) ----
        {
            const unsigned short* kp = base + (size_t)(kt * 32 + srow) * DQKV + 768 + schunk * 8;
            bf16x8 kv = *reinterpret_cast<const bf16x8*>(kp);
            *reinterpret_cast<bf16x8*>(&Ks[srow * 64 + ((schunk ^ (srow & 7)) * 8)]) = kv;
        }
        // ---- stage V tile transposed: Vt[d][krow] ----
        {
            unsigned short vv[8];
            #pragma unroll
            for (int j = 0; j < 8; ++j)
                vv[j] = base[(size_t)(kt * 32 + vw * 8 + j) * DQKV + 1536 + vd];
            uint4 pk;
            pk.x = vv[0] | ((unsigned)vv[1] << 16);
            pk.y = vv[2] | ((unsigned)vv[3] << 16);
            pk.z = vv[4] | ((unsigned)vv[5] << 16);
            pk.w = vv[6] | ((unsigned)vv[7] << 16);
            *reinterpret_cast<uint4*>(&Vt[vd * 40 + vw * 8]) = pk;
        }
        __syncthreads();

        // ---- QK^T: S[q][kcol], 2 col-tiles x 2 k-steps ----
        f32x4 s_acc[2] = {};
        #pragma unroll
        for (int t = 0; t < 2; ++t) {
            const int kr = t * 16 + c;
            #pragma unroll
            for (int ks = 0; ks < 2; ++ks) {
                bf16x8 kf = *reinterpret_cast<const bf16x8*>(
                    &Ks[kr * 64 + (((ks * 4 + g) ^ (kr & 7)) * 8)]);
                s_acc[t] = __builtin_amdgcn_mfma_f32_16x16x32_bf16(qf[ks], kf, s_acc[t], 0, 0, 0);
            }
        }
        // scale + causal mask
        float sc[2][4];
        #pragma unroll
        for (int t = 0; t < 2; ++t) {
            const int kglob = kt * 32 + t * 16 + c;
            #pragma unroll
            for (int r = 0; r < 4; ++r) {
                float v = s_acc[t][r] * 0.125f;
                sc[t][r] = (kglob > q0 + g * 4 + r) ? -1e30f : v;
            }
        }
        // online softmax (per q-row r, reduce across the 16 c-lanes)
        float pout[2][4];
        #pragma unroll
        for (int r = 0; r < 4; ++r) {
            float tmax = fmaxf(sc[0][r], sc[1][r]);
            #pragma unroll
            for (int ms = 1; ms < 16; ms <<= 1) tmax = fmaxf(tmax, __shfl_xor(tmax, ms));
            float mnew = fmaxf(m_run[r], tmax);
            float alpha = __expf(m_run[r] - mnew);
            float p0 = __expf(sc[0][r] - mnew);
            float p1 = __expf(sc[1][r] - mnew);
            float psum = p0 + p1;
            #pragma unroll
            for (int ms = 1; ms < 16; ms <<= 1) psum += __shfl_xor(psum, ms);
            l_run[r] = l_run[r] * alpha + psum;
            m_run[r] = mnew;
            #pragma unroll
            for (int dt = 0; dt < 4; ++dt) o_acc[dt][r] *= alpha;
            pout[0][r] = p0; pout[1][r] = p1;
        }
        // ---- P transpose via LDS: write packed bf16 pairs [q][krow/2] ----
        #pragma unroll
        for (int t = 0; t < 2; ++t) {
            #pragma unroll
            for (int r = 0; r < 4; ++r) {
                int my = f2bf(pout[t][r]);
                int part = __shfl_xor(my, 1);
                unsigned int word = (c & 1) ? ((unsigned)(part & 0xffff) | ((unsigned)my << 16))
                                            : ((unsigned)(my & 0xffff) | ((unsigned)part << 16));
                Ps[w][(g * 4 + r) * 20 + t * 8 + (c >> 1)] = word;
            }
        }
        // A-fragment of P: row=c, k=g*8+j  -> one aligned 16B read
        uint4 praw = *reinterpret_cast<const uint4*>(&Ps[w][c * 20 + g * 4]);
        bf16x8 pf = *reinterpret_cast<const bf16x8*>(&praw);
        // ---- PV: O += P @ V ----
        #pragma unroll
        for (int dt = 0; dt < 4; ++dt) {
            bf16x8 vf = *reinterpret_cast<const bf16x8*>(&Vt[(dt * 16 + c) * 40 + g * 8]);
            o_acc[dt] = __builtin_amdgcn_mfma_f32_16x16x32_bf16(pf, vf, o_acc[dt], 0, 0, 0);
        }
        __syncthreads();
    }

    // ---- epilogue ----
    float inv[4];
    #pragma unroll
    for (int r = 0; r < 4; ++r) inv[r] = 1.0f / l_run[r];
    #pragma unroll
    for (int r = 0; r < 4; ++r) {
        unsigned short* op = ao + (size_t)(b * SEQ + q0 + g * 4 + r) * D_MODEL + h * HEAD + c;
        #pragma unroll
        for (int dt = 0; dt < 4; ++dt)
            op[dt * 16] = f2bf(o_acc[dt][r] * inv[r]);
    }
}

extern "C" void kernel_launch(void* const* d_in, const int* in_sizes, int n_in,
                              void* d_out, int out_size, void* d_ws, size_t ws_size,
                              hipStream_t stream) {
    const int*   idx     = (const int*)  d_in[0];
    const float* tok_emb = (const float*)d_in[1];
    const float* pos_emb = (const float*)d_in[2];
    const float* Wq      = (const float*)d_in[3];
    const float* bq      = (const float*)d_in[4];
    const float* Wk      = (const float*)d_in[5];
    const float* bk      = (const float*)d_in[6];
    const float* Wv      = (const float*)d_in[7];
    const float* bv      = (const float*)d_in[8];
    const float* Wproj   = (const float*)d_in[9];
    const float* bproj   = (const float*)d_in[10];
    const float* ln1g    = (const float*)d_in[11];
    const float* ln1b    = (const float*)d_in[12];
    const float* ln2g    = (const float*)d_in[13];
    const float* ln2b    = (const float*)d_in[14];
    const float* Wf1     = (const float*)d_in[15];
    const float* bf1     = (const float*)d_in[16];
    const float* Wf2     = (const float*)d_in[17];
    const float* bf2     = (const float*)d_in[18];
    const float* lnfg    = (const float*)d_in[19];
    const float* lnfb    = (const float*)d_in[20];
    const float* Wlm     = (const float*)d_in[21];
    float* outp = (float*)d_out;

    char* basep = (char*)d_ws;
    size_t off = 0;
    auto alloc = [&](size_t bytes) -> void* {
        void* p = basep + off;
        off = (off + bytes + 255) & ~(size_t)255;
        return p;
    };
    float*          x      = (float*)         alloc((size_t)NROWS * D_MODEL * 4);
    unsigned short* qkv    = (unsigned short*)alloc((size_t)NROWS * DQKV * 2);
    unsigned short* hb     = (unsigned short*)alloc((size_t)NROWS * D_MODEL * 2);
    unsigned short* ao     = (unsigned short*)alloc((size_t)NROWS * D_MODEL * 2);
    unsigned short* mid    = (unsigned short*)alloc((size_t)NROWS * DFFN * 2);
    unsigned short* Wqkvb  = (unsigned short*)alloc((size_t)NLAYER * DQKV * D_MODEL * 2);
    unsigned short* Wprojb = (unsigned short*)alloc((size_t)NLAYER * D_MODEL * D_MODEL * 2);
    unsigned short* Wf1b   = (unsigned short*)alloc((size_t)NLAYER * DFFN * D_MODEL * 2);
    unsigned short* Wf2b   = (unsigned short*)alloc((size_t)NLAYER * D_MODEL * DFFN * 2);
    unsigned short* Wlmb   = (unsigned short*)alloc((size_t)VPAD * D_MODEL * 2);
    float*          bqkv   = (float*)         alloc((size_t)NLAYER * DQKV * 4);

    dim3 blk(256);
    dim3 tblk(32, 8);

    conv_lm<<<2048, blk, 0, stream>>>(Wlm, Wlmb);
    conv_transpose<1><<<dim3(24, 24, 6), tblk, 0, stream>>>(Wq, Wqkvb,             768, 768,  (size_t)768*768,  (size_t)DQKV*768);
    conv_transpose<1><<<dim3(24, 24, 6), tblk, 0, stream>>>(Wk, Wqkvb + 768*768,   768, 768,  (size_t)768*768,  (size_t)DQKV*768);
    conv_transpose<1><<<dim3(24, 24, 6), tblk, 0, stream>>>(Wv, Wqkvb + 2*768*768, 768, 768,  (size_t)768*768,  (size_t)DQKV*768);
    conv_transpose<0><<<dim3(24, 24, 6), tblk, 0, stream>>>(Wproj, Wprojb,         768, 768,  (size_t)768*768,  (size_t)768*768);
    conv_transpose<0><<<dim3(96, 24, 6), tblk, 0, stream>>>(Wf1, Wf1b,             768, 3072, (size_t)768*3072, (size_t)3072*768);
    conv_transpose<0><<<dim3(24, 96, 6), tblk, 0, stream>>>(Wf2, Wf2b,             3072, 768, (size_t)3072*768, (size_t)768*3072);
    conv_bias<<<(NLAYER * DQKV + 255) / 256, blk, 0, stream>>>(bq, bk, bv, bqkv);

    embed_kernel<<<NROWS, blk, 0, stream>>>(idx, tok_emb, pos_emb, x);

    dim3 gqkv(18 * 32);                  // 1D grids (XCD swizzle inside)
    dim3 g768(6 * 32);
    dim3 g3072(24 * 32);
    dim3 ga(SEQ / 64, N_HEAD, BATCH);    // (16, 12, 4)

    for (int li = 0; li < NLAYER; ++li) {
        ln_kernel<<<NROWS, blk, 0, stream>>>(x, ln1g + li * D_MODEL, ln1b + li * D_MODEL, hb);

        gemm_mfma<1, false, false><<<gqkv, blk, 0, stream>>>(
            hb, Wqkvb + (size_t)li * DQKV * D_MODEL, bqkv + li * DQKV, nullptr,
            qkv, NROWS, DQKV, D_MODEL);

        attn_mfma<<<ga, blk, 0, stream>>>(qkv, ao);

        gemm_mfma<0, false, true><<<g768, blk, 0, stream>>>(
            ao, Wprojb + (size_t)li * D_MODEL * D_MODEL, bproj + li * D_MODEL, x,
            x, NROWS, D_MODEL, D_MODEL);

        ln_kernel<<<NROWS, blk, 0, stream>>>(x, ln2g + li * D_MODEL, ln2b + li * D_MODEL, hb);

        gemm_mfma<1, true, false><<<g3072, blk, 0, stream>>>(
            hb, Wf1b + (size_t)li * DFFN * D_MODEL, bf1 + li * DFFN, nullptr,
            mid, NROWS, DFFN, D_MODEL);

        gemm_mfma<0, false, true><<<g768, blk, 0, stream>>>(
            mid, Wf2b + (size_t)li * D_MODEL * DFFN, bf2 + li * D_MODEL, x,
            x, NROWS, D_MODEL, DFFN);
    }

    ln_kernel<<<NROWS, blk, 0, stream>>>(x, lnfg, lnfb, hb);

    dim3 gl(393 * 32);
    gemm_mfma<0, false, false><<<gl, blk, 0, stream>>>(
        hb, Wlmb, nullptr, nullptr, outp, NROWS, VOCAB, D_MODEL);
}

// Round 4
// 3168.509 us; speedup vs baseline: 6.3991x; 1.1242x over previous
//
#include <hip/hip_runtime.h>
#include <hip/hip_bf16.h>
#include <math.h>

#define D_MODEL 768
#define N_HEAD  12
#define HEAD    64
#define SEQ     1024
#define NLAYER  6
#define BATCH   4
#define NROWS   (BATCH*SEQ)   // 4096
#define VOCAB   50257
#define VPAD    50304         // 393*128
#define DFFN    3072
#define DQKV    2304

typedef __attribute__((ext_vector_type(8))) __bf16 bf16x8;
typedef __attribute__((ext_vector_type(4))) float f32x4;
typedef __attribute__((ext_vector_type(4))) unsigned short u16x4;

__device__ inline unsigned short f2bf(float x) {
    __hip_bfloat16 h = __float2bfloat16(x);
    return *reinterpret_cast<unsigned short*>(&h);
}

// ---------------- embedding ----------------
__global__ __launch_bounds__(256)
void embed_kernel(const int* __restrict__ idx, const float* __restrict__ tok,
                  const float* __restrict__ pos, float* __restrict__ x) {
    int row = blockIdx.x;
    int t = idx[row];
    int s = row & (SEQ - 1);
    const float* tp = tok + (size_t)t * D_MODEL;
    const float* pp = pos + (size_t)s * D_MODEL;
    float* xp = x + (size_t)row * D_MODEL;
    for (int i = threadIdx.x; i < D_MODEL; i += 256) xp[i] = tp[i] + pp[i];
}

// ---------------- layernorm: fp32 in, bf16 out ----------------
__global__ __launch_bounds__(256)
void ln_kernel(const float* __restrict__ in, const float* __restrict__ gw,
               const float* __restrict__ bw, unsigned short* __restrict__ out) {
    int row = blockIdx.x;
    int tid = threadIdx.x;
    const float* x = in + (size_t)row * D_MODEL;
    float v0 = x[tid], v1 = x[tid + 256], v2 = x[tid + 512];
    float s  = v0 + v1 + v2;
    float sq = v0*v0 + v1*v1 + v2*v2;
    #pragma unroll
    for (int o = 1; o < 64; o <<= 1) { s += __shfl_xor(s, o); sq += __shfl_xor(sq, o); }
    __shared__ float red[8];
    int wave = tid >> 6;
    if ((tid & 63) == 0) { red[wave] = s; red[4 + wave] = sq; }
    __syncthreads();
    s  = red[0] + red[1] + red[2] + red[3];
    sq = red[4] + red[5] + red[6] + red[7];
    float mean = s * (1.0f / D_MODEL);
    float var  = sq * (1.0f / D_MODEL) - mean * mean;
    float rstd = rsqrtf(var + 1e-5f);
    unsigned short* op = out + (size_t)row * D_MODEL;
    op[tid]       = f2bf((v0 - mean) * rstd * gw[tid]       + bw[tid]);
    op[tid + 256] = f2bf((v1 - mean) * rstd * gw[tid + 256] + bw[tid + 256]);
    op[tid + 512] = f2bf((v2 - mean) * rstd * gw[tid + 512] + bw[tid + 512]);
}

// ---------------- weight conversion ----------------
template<int MODE>
__global__ __launch_bounds__(256)
void conv_transpose(const float* __restrict__ in, unsigned short* __restrict__ out,
                    int K, int N, size_t inLstride, size_t outLstride) {
    __shared__ float t[32][33];
    const int tx = threadIdx.x, ty = threadIdx.y;
    const int n0 = blockIdx.x * 32, k0 = blockIdx.y * 32;
    const float* ip = in + blockIdx.z * inLstride;
    unsigned short* op = out + blockIdx.z * outLstride;
    #pragma unroll
    for (int j = 0; j < 4; ++j) {
        int k = k0 + ty + j * 8, n = n0 + tx;
        float v = (MODE == 0) ? ip[(size_t)k * N + n]
                              : ip[(size_t)((n >> 6) * K + k) * 64 + (n & 63)];
        t[ty + j * 8][tx] = v;
    }
    __syncthreads();
    #pragma unroll
    for (int j = 0; j < 4; ++j) {
        int n = n0 + ty + j * 8, k = k0 + tx;
        op[(size_t)n * K + k] = f2bf(t[tx][ty + j * 8]);
    }
}

__global__ __launch_bounds__(256)
void conv_lm(const float* __restrict__ in, unsigned short* __restrict__ out) {
    const int nchunks = VPAD * D_MODEL / 4;
    const int vchunks = VOCAB * D_MODEL / 4;
    for (int i = blockIdx.x * 256 + threadIdx.x; i < nchunks; i += gridDim.x * 256) {
        u16x4 o;
        if (i < vchunks) {
            float4 v = reinterpret_cast<const float4*>(in)[i];
            o[0] = f2bf(v.x); o[1] = f2bf(v.y); o[2] = f2bf(v.z); o[3] = f2bf(v.w);
        } else { o[0] = 0; o[1] = 0; o[2] = 0; o[3] = 0; }
        reinterpret_cast<u16x4*>(out)[i] = o;
    }
}

__global__ __launch_bounds__(256)
void conv_bias(const float* __restrict__ bq, const float* __restrict__ bk,
               const float* __restrict__ bv, float* __restrict__ out) {
    int i = blockIdx.x * 256 + threadIdx.x;
    if (i >= NLAYER * DQKV) return;
    int l = i / DQKV, n = i % DQKV;
    float v;
    if (n < 768)        v = bq[l * 768 + n];
    else if (n < 1536)  v = bk[l * 768 + n - 768];
    else                v = bv[l * 768 + n - 1536];
    out[i] = v;
}

// ---------------- bf16 MFMA GEMM ----------------
// C[M,N] = A[M,K](bf16) @ B[N,K](bf16)^T + bias (+GELU) (+res)
// 1D grid, nwg = (M/BM)*(N/128), nwg%8==0, (M/BM)%8==0.
// Block order: XCD-contiguous chunks; within chunk by fastest (groups of 8 rows),
// bx advances slowly -> A-slab L2-resident per XCD, B fetched from HBM once.
template<int BM, int OUTF /*0=f32,1=bf16*/, bool GELU, bool RES>
__global__ __launch_bounds__(256)
void gemm_mfma(const unsigned short* __restrict__ A, const unsigned short* __restrict__ B,
               const float* __restrict__ bias, const float* __restrict__ res,
               void* __restrict__ Cout, int M, int N, int K) {
    __shared__ bf16x8 As[BM * 8];   // [c][row]: index c*BM+row
    __shared__ bf16x8 Bs[1024];     // [c][col]: index c*128+col
    const int nwg = gridDim.x;
    const int t = (blockIdx.x & 7) * (nwg >> 3) + (blockIdx.x >> 3);
    const int MT = M / BM;
    const int NBX = nwg / MT;
    const int srsize = NBX * 8;
    const int sr = t / srsize;
    const int rem = t - sr * srsize;
    const int bx = rem >> 3;
    const int by = sr * 8 + (rem & 7);
    const int bm = by * BM, bn = bx * 128;
    const int tid = threadIdx.x;
    const int l = tid & 63, w = tid >> 6;
    constexpr int MI = (BM == 128) ? 4 : 2;
    const int wr = (BM == 128) ? (w >> 1) * 64 : (w & 1) * 32;
    const int wc = (BM == 128) ? (w & 1) * 64 : (w >> 1) * 64;
    f32x4 acc[MI][4] = {};
    for (int k0 = 0; k0 < K; k0 += 64) {
        #pragma unroll
        for (int p = 0; p < BM * 8 / 256; ++p) {
            int u = p * 256 + tid;
            int row = u % BM, c = u / BM;
            const unsigned short* ga = A + (size_t)(bm + row) * K + k0 + c * 8;
            __builtin_amdgcn_global_load_lds(
                (const __attribute__((address_space(1))) unsigned int*)ga,
                (__attribute__((address_space(3))) unsigned int*)(&As[u]), 16, 0, 0);
        }
        #pragma unroll
        for (int p = 0; p < 4; ++p) {
            int u = p * 256 + tid;
            int col = u & 127, c = u >> 7;
            const unsigned short* gb = B + (size_t)(bn + col) * K + k0 + c * 8;
            __builtin_amdgcn_global_load_lds(
                (const __attribute__((address_space(1))) unsigned int*)gb,
                (__attribute__((address_space(3))) unsigned int*)(&Bs[u]), 16, 0, 0);
        }
        __syncthreads();
        #pragma unroll
        for (int s = 0; s < 2; ++s) {
            const int cidx = s * 4 + (l >> 4);
            bf16x8 af[MI], bfr[4];
            #pragma unroll
            for (int mi = 0; mi < MI; ++mi) af[mi]  = As[cidx * BM + wr + mi * 16 + (l & 15)];
            #pragma unroll
            for (int ni = 0; ni < 4; ++ni)  bfr[ni] = Bs[cidx * 128 + wc + ni * 16 + (l & 15)];
            #pragma unroll
            for (int mi = 0; mi < MI; ++mi)
                #pragma unroll
                for (int ni = 0; ni < 4; ++ni)
                    acc[mi][ni] = __builtin_amdgcn_mfma_f32_16x16x32_bf16(
                        af[mi], bfr[ni], acc[mi][ni], 0, 0, 0);
        }
        __syncthreads();
    }
    #pragma unroll
    for (int mi = 0; mi < MI; ++mi) {
        #pragma unroll
        for (int r = 0; r < 4; ++r) {
            const int row = bm + wr + mi * 16 + (l >> 4) * 4 + r;
            #pragma unroll
            for (int ni = 0; ni < 4; ++ni) {
                const int col = bn + wc + ni * 16 + (l & 15);
                if (col < N) {
                    float v = acc[mi][ni][r];
                    if (bias) v += bias[col];
                    if (GELU) v = 0.5f * v * (1.0f + erff(v * 0.70710678118654752f));
                    if (RES)  v += res[(size_t)row * N + col];
                    if (OUTF == 0) ((float*)Cout)[(size_t)row * N + col] = v;
                    else ((unsigned short*)Cout)[(size_t)row * N + col] = f2bf(v);
                }
            }
        }
    }
}

// ---------------- bf16 MFMA causal flash attention ----------------
__global__ __launch_bounds__(256)
void attn_mfma(const unsigned short* __restrict__ qkv, unsigned short* __restrict__ ao) {
    const int qt = gridDim.x - 1 - blockIdx.x;   // heavy blocks first
    const int h = blockIdx.y, b = blockIdx.z;
    const int tid = threadIdx.x;
    const int w = tid >> 6, l = tid & 63;
    const int c = l & 15, g = l >> 4;

    __shared__ unsigned short Ks[32 * 64];       // row-major, 16B-chunk XOR swizzle
    __shared__ unsigned short Vt[64 * 40];       // [d][krow], row pad 40 halves
    __shared__ unsigned int   Ps[4][16 * 20];    // per-wave P transpose

    const unsigned short* base = qkv + (size_t)(b * SEQ) * DQKV + h * HEAD;
    const int q0 = qt * 64 + w * 16;

    bf16x8 qf[2];
    {
        const unsigned short* qp = base + (size_t)(q0 + c) * DQKV + g * 8;
        qf[0] = *reinterpret_cast<const bf16x8*>(qp);
        qf[1] = *reinterpret_cast<const bf16x8*>(qp + 32);
    }

    f32x4 o_acc[4] = {};
    float m_run[4]  = {-INFINITY, -INFINITY, -INFINITY, -INFINITY};
    float l_run[4]  = {0.f, 0.f, 0.f, 0.f};

    const int srow = tid >> 3, schunk = tid & 7;
    const int vd = tid & 63, vw = tid >> 6;

    const int nkt = 2 * qt + 2;
    for (int kt = 0; kt < nkt; ++kt) {
        {
            const unsigned short* kp = base + (size_t)(kt * 32 + srow) * DQKV + 768 + schunk * 8;
            bf16x8 kv = *reinterpret_cast<const bf16x8*>(kp);
            *reinterpret_cast<bf16x8*>(&Ks[srow * 64 + ((schunk ^ (srow & 7)) * 8)]) = kv;
        }
        {
            unsigned short vv[8];
            #pragma unroll
            for (int j = 0; j < 8; ++j)
                vv[j] = base[(size_t)(kt * 32 + vw * 8 + j) * DQKV + 1536 + vd];
            uint4 pk;
            pk.x = vv[0] | ((unsigned)vv[1] << 16);
            pk.y = vv[2] | ((unsigned)vv[3] << 16);
            pk.z = vv[4] | ((unsigned)vv[5] << 16);
            pk.w = vv[6] | ((unsigned)vv[7] << 16);
            *reinterpret_cast<uint4*>(&Vt[vd * 40 + vw * 8]) = pk;
        }
        __syncthreads();

        f32x4 s_acc[2] = {};
        #pragma unroll
        for (int t = 0; t < 2; ++t) {
            const int kr = t * 16 + c;
            #pragma unroll
            for (int ks = 0; ks < 2; ++ks) {
                bf16x8 kf = *reinterpret_cast<const bf16x8*>(
                    &Ks[kr * 64 + (((ks * 4 + g) ^ (kr & 7)) * 8)]);
                s_acc[t] = __builtin_amdgcn_mfma_f32_16x16x32_bf16(qf[ks], kf, s_acc[t], 0, 0, 0);
            }
        }
        float sc[2][4];
        #pragma unroll
        for (int t = 0; t < 2; ++t) {
            const int kglob = kt * 32 + t * 16 + c;
            #pragma unroll
            for (int r = 0; r < 4; ++r) {
                float v = s_acc[t][r] * 0.125f;
                sc[t][r] = (kglob > q0 + g * 4 + r) ? -1e30f : v;
            }
        }
        float pout[2][4];
        #pragma unroll
        for (int r = 0; r < 4; ++r) {
            float tmax = fmaxf(sc[0][r], sc[1][r]);
            #pragma unroll
            for (int ms = 1; ms < 16; ms <<= 1) tmax = fmaxf(tmax, __shfl_xor(tmax, ms));
            float mnew = fmaxf(m_run[r], tmax);
            float alpha = __expf(m_run[r] - mnew);
            float p0 = __expf(sc[0][r] - mnew);
            float p1 = __expf(sc[1][r] - mnew);
            float psum = p0 + p1;
            #pragma unroll
            for (int ms = 1; ms < 16; ms <<= 1) psum += __shfl_xor(psum, ms);
            l_run[r] = l_run[r] * alpha + psum;
            m_run[r] = mnew;
            #pragma unroll
            for (int dt = 0; dt < 4; ++dt) o_acc[dt][r] *= alpha;
            pout[0][r] = p0; pout[1][r] = p1;
        }
        #pragma unroll
        for (int t = 0; t < 2; ++t) {
            #pragma unroll
            for (int r = 0; r < 4; ++r) {
                int my = f2bf(pout[t][r]);
                int part = __shfl_xor(my, 1);
                unsigned int word = (c & 1) ? ((unsigned)(part & 0xffff) | ((unsigned)my << 16))
                                            : ((unsigned)(my & 0xffff) | ((unsigned)part << 16));
                Ps[w][(g * 4 + r) * 20 + t * 8 + (c >> 1)] = word;
            }
        }
        uint4 praw = *reinterpret_cast<const uint4*>(&Ps[w][c * 20 + g * 4]);
        bf16x8 pf = *reinterpret_cast<const bf16x8*>(&praw);
        #pragma unroll
        for (int dt = 0; dt < 4; ++dt) {
            bf16x8 vf = *reinterpret_cast<const bf16x8*>(&Vt[(dt * 16 + c) * 40 + g * 8]);
            o_acc[dt] = __builtin_amdgcn_mfma_f32_16x16x32_bf16(pf, vf, o_acc[dt], 0, 0, 0);
        }
        __syncthreads();
    }

    float inv[4];
    #pragma unroll
    for (int r = 0; r < 4; ++r) inv[r] = 1.0f / l_run[r];
    #pragma unroll
    for (int r = 0; r < 4; ++r) {
        unsigned short* op = ao + (size_t)(b * SEQ + q0 + g * 4 + r) * D_MODEL + h * HEAD + c;
        #pragma unroll
        for (int dt = 0; dt < 4; ++dt)
            op[dt * 16] = f2bf(o_acc[dt][r] * inv[r]);
    }
}

extern "C" void kernel_launch(void* const* d_in, const int* in_sizes, int n_in,
                              void* d_out, int out_size, void* d_ws, size_t ws_size,
                              hipStream_t stream) {
    const int*   idx     = (const int*)  d_in[0];
    const float* tok_emb = (const float*)d_in[1];
    const float* pos_emb = (const float*)d_in[2];
    const float* Wq      = (const float*)d_in[3];
    const float* bq      = (const float*)d_in[4];
    const float* Wk      = (const float*)d_in[5];
    const float* bk      = (const float*)d_in[6];
    const float* Wv      = (const float*)d_in[7];
    const float* bv      = (const float*)d_in[8];
    const float* Wproj   = (const float*)d_in[9];
    const float* bproj   = (const float*)d_in[10];
    const float* ln1g    = (const float*)d_in[11];
    const float* ln1b    = (const float*)d_in[12];
    const float* ln2g    = (const float*)d_in[13];
    const float* ln2b    = (const float*)d_in[14];
    const float* Wf1     = (const float*)d_in[15];
    const float* bf1     = (const float*)d_in[16];
    const float* Wf2     = (const float*)d_in[17];
    const float* bf2     = (const float*)d_in[18];
    const float* lnfg    = (const float*)d_in[19];
    const float* lnfb    = (const float*)d_in[20];
    const float* Wlm     = (const float*)d_in[21];
    float* outp = (float*)d_out;

    char* basep = (char*)d_ws;
    size_t off = 0;
    auto alloc = [&](size_t bytes) -> void* {
        void* p = basep + off;
        off = (off + bytes + 255) & ~(size_t)255;
        return p;
    };
    float*          x      = (float*)         alloc((size_t)NROWS * D_MODEL * 4);
    unsigned short* qkv    = (unsigned short*)alloc((size_t)NROWS * DQKV * 2);
    unsigned short* hb     = (unsigned short*)alloc((size_t)NROWS * D_MODEL * 2);
    unsigned short* ao     = (unsigned short*)alloc((size_t)NROWS * D_MODEL * 2);
    unsigned short* mid    = (unsigned short*)alloc((size_t)NROWS * DFFN * 2);
    unsigned short* Wqkvb  = (unsigned short*)alloc((size_t)NLAYER * DQKV * D_MODEL * 2);
    unsigned short* Wprojb = (unsigned short*)alloc((size_t)NLAYER * D_MODEL * D_MODEL * 2);
    unsigned short* Wf1b   = (unsigned short*)alloc((size_t)NLAYER * DFFN * D_MODEL * 2);
    unsigned short* Wf2b   = (unsigned short*)alloc((size_t)NLAYER * D_MODEL * DFFN * 2);
    unsigned short* Wlmb   = (unsigned short*)alloc((size_t)VPAD * D_MODEL * 2);
    float*          bqkv   = (float*)         alloc((size_t)NLAYER * DQKV * 4);

    dim3 blk(256);
    dim3 tblk(32, 8);

    conv_lm<<<2048, blk, 0, stream>>>(Wlm, Wlmb);
    conv_transpose<1><<<dim3(24, 24, 6), tblk, 0, stream>>>(Wq, Wqkvb,             768, 768,  (size_t)768*768,  (size_t)DQKV*768);
    conv_transpose<1><<<dim3(24, 24, 6), tblk, 0, stream>>>(Wk, Wqkvb + 768*768,   768, 768,  (size_t)768*768,  (size_t)DQKV*768);
    conv_transpose<1><<<dim3(24, 24, 6), tblk, 0, stream>>>(Wv, Wqkvb + 2*768*768, 768, 768,  (size_t)768*768,  (size_t)DQKV*768);
    conv_transpose<0><<<dim3(24, 24, 6), tblk, 0, stream>>>(Wproj, Wprojb,         768, 768,  (size_t)768*768,  (size_t)768*768);
    conv_transpose<0><<<dim3(96, 24, 6), tblk, 0, stream>>>(Wf1, Wf1b,             768, 3072, (size_t)768*3072, (size_t)3072*768);
    conv_transpose<0><<<dim3(24, 96, 6), tblk, 0, stream>>>(Wf2, Wf2b,             3072, 768, (size_t)3072*768, (size_t)768*3072);
    conv_bias<<<(NLAYER * DQKV + 255) / 256, blk, 0, stream>>>(bq, bk, bv, bqkv);

    embed_kernel<<<NROWS, blk, 0, stream>>>(idx, tok_emb, pos_emb, x);

    dim3 gqkv(18 * 32);                  // BM=128
    dim3 g768s(6 * 64);                  // BM=64  (proj, FFN2)
    dim3 g3072(24 * 32);                 // BM=128
    dim3 ga(SEQ / 64, N_HEAD, BATCH);    // (16, 12, 4)

    for (int li = 0; li < NLAYER; ++li) {
        ln_kernel<<<NROWS, blk, 0, stream>>>(x, ln1g + li * D_MODEL, ln1b + li * D_MODEL, hb);

        gemm_mfma<128, 1, false, false><<<gqkv, blk, 0, stream>>>(
            hb, Wqkvb + (size_t)li * DQKV * D_MODEL, bqkv + li * DQKV, nullptr,
            qkv, NROWS, DQKV, D_MODEL);

        attn_mfma<<<ga, blk, 0, stream>>>(qkv, ao);

        gemm_mfma<64, 0, false, true><<<g768s, blk, 0, stream>>>(
            ao, Wprojb + (size_t)li * D_MODEL * D_MODEL, bproj + li * D_MODEL, x,
            x, NROWS, D_MODEL, D_MODEL);

        ln_kernel<<<NROWS, blk, 0, stream>>>(x, ln2g + li * D_MODEL, ln2b + li * D_MODEL, hb);

        gemm_mfma<128, 1, true, false><<<g3072, blk, 0, stream>>>(
            hb, Wf1b + (size_t)li * DFFN * D_MODEL, bf1 + li * DFFN, nullptr,
            mid, NROWS, DFFN, D_MODEL);

        gemm_mfma<64, 0, false, true><<<g768s, blk, 0, stream>>>(
            mid, Wf2b + (size_t)li * D_MODEL * DFFN, bf2 + li * D_MODEL, x,
            x, NROWS, D_MODEL, DFFN);
    }

    ln_kernel<<<NROWS, blk, 0, stream>>>(x, lnfg, lnfb, hb);

    dim3 gl(393 * 32);
    gemm_mfma<128, 0, false, false><<<gl, blk, 0, stream>>>(
        hb, Wlmb, nullptr, nullptr, outp, NROWS, VOCAB, D_MODEL);
}